// Round 10
// baseline (321.737 us; speedup 1.0000x reference)
//
#include <hip/hip_runtime.h>

#define NG 72

// ---------------- conv1: (64,216,46,46) -> k5 g72 (3->8) -> relu -> pool2 -> (64,576,21,21)
// Two blocks per (b,g) (pooled rows 0-10 / 11-20). Weights block-uniform ->
// s_load/SGPR operands. Input tile plain pitch-48 layout: window rows read as
// 3 aligned float2 (ds_read_b64, 2-way conflict = free per m136) -> 54 LDS
// instrs/thread (was 108 scalar b32).
__global__ __launch_bounds__(256) void conv1_k(const float* __restrict__ x,
                                               const float* __restrict__ w,
                                               const float* __restrict__ bias,
                                               float* __restrict__ out) {
  const int blk = blockIdx.x;
  const int b = blk / (NG * 2), rem = blk % (NG * 2), g = rem >> 1, yh = rem & 1;
  const int y0 = yh ? 11 : 0;          // pooled-row base
  const int ny = yh ? 10 : 11;         // pooled rows this block
  const int r0 = 2 * y0;               // first input row staged
  const int nr = yh ? 24 : 26;         // input rows staged
  __shared__ float sx[3][26][48];      // pitch 48 floats = 192B: rows 8B-aligned
  const float* xp = x + (size_t)(b * 216 + g * 3) * 2116;
  const int nf4 = (nr * 46) >> 2;      // 299 or 276 float4 per ic (both exact)
#pragma unroll
  for (int ic = 0; ic < 3; ic++) {
    const float4* src4 = (const float4*)(xp + ic * 2116 + r0 * 46);  // 16B-aligned
    for (int i = threadIdx.x; i < nf4; i += 256) {
      const float4 v = src4[i];
#pragma unroll
      for (int j = 0; j < 4; j++) {
        const int k = 4 * i + j;
        sx[ic][k / 46][k % 46] = (&v.x)[j];
      }
    }
  }
  __syncthreads();
  const float* wg = w + (size_t)(g * 8) * 75;   // uniform base -> scalar loads
  const float* bg = bias + g * 8;               // uniform
  const int tid = threadIdx.x;
  if (tid < ny * 21) {
    const int yl = tid / 21, px = tid % 21;
    const int iy = 2 * yl, ix = 2 * px;         // ix even -> 8B-aligned float2
    float acc[8][4];
#pragma unroll
    for (int o = 0; o < 8; o++)
#pragma unroll
      for (int q = 0; q < 4; q++) acc[o][q] = 0.f;
#pragma unroll
    for (int ic = 0; ic < 3; ic++) {
      float win[6][6];
#pragma unroll
      for (int r = 0; r < 6; r++)
#pragma unroll
        for (int j2 = 0; j2 < 3; j2++) {
          const float2 v = *(const float2*)&sx[ic][iy + r][ix + 2 * j2];
          win[r][2 * j2] = v.x; win[r][2 * j2 + 1] = v.y;
        }
#pragma unroll
      for (int oc = 0; oc < 8; oc++) {
        const float* wq = wg + (oc * 3 + ic) * 25;   // uniform -> SGPR
#pragma unroll
        for (int ky = 0; ky < 5; ky++)
#pragma unroll
          for (int kx = 0; kx < 5; kx++) {
            const float wv_ = wq[ky * 5 + kx];
            acc[oc][0] = fmaf(win[ky][kx],         wv_, acc[oc][0]);
            acc[oc][1] = fmaf(win[ky][kx + 1],     wv_, acc[oc][1]);
            acc[oc][2] = fmaf(win[ky + 1][kx],     wv_, acc[oc][2]);
            acc[oc][3] = fmaf(win[ky + 1][kx + 1], wv_, acc[oc][3]);
          }
      }
    }
#pragma unroll
    for (int oc = 0; oc < 8; oc++) {
      const float v = fmaxf(fmaxf(acc[oc][0], acc[oc][1]), fmaxf(acc[oc][2], acc[oc][3])) + bg[oc];
      out[(size_t)(b * 576 + g * 8 + oc) * 441 + (y0 + yl) * 21 + px] = fmaxf(v, 0.f);
    }
  }
}

// ---------------- conv2: (64,576,21,21) -> k3 (8->16) -> relu -> pool2 -> (64,1152,9,9)
// Uniform global weights (SGPR), all 16 oc in one pass (acc 64 + win 16 VGPR).
#define C2_NBB 3
__global__ __launch_bounds__(256) void conv2_k(const float* __restrict__ x,
                                               const float* __restrict__ w,
                                               const float* __restrict__ bias,
                                               float* __restrict__ out) {
  const int g = blockIdx.x % NG, b0 = (blockIdx.x / NG) * C2_NBB;
  const int nbb = min(C2_NBB, 64 - b0);
  __shared__ float sx[C2_NBB][8][21][22];
  for (int bb = 0; bb < nbb; bb++) {
    const float* xp = x + (size_t)((b0 + bb) * 576 + g * 8) * 441;
    for (int i = threadIdx.x; i < 8 * 441; i += 256) {
      const int ic = i / 441, rem = i % 441, r = rem / 21, c = rem % 21;
      sx[bb][ic][r][c] = xp[i];
    }
  }
  __syncthreads();
  const float* wg = w + (size_t)(g * 16) * 72;   // uniform
  const float* bg = bias + g * 16;               // uniform
  for (int u = threadIdx.x; u < nbb * 81; u += 256) {
    const int bb = u / 81, p = u % 81, py = p / 9, px = p % 9;
    const int iy = 2 * py, ix = 2 * px;
    float acc[16][4];
#pragma unroll
    for (int o = 0; o < 16; o++)
#pragma unroll
      for (int q = 0; q < 4; q++) acc[o][q] = 0.f;
#pragma unroll
    for (int ic = 0; ic < 8; ic++) {
      float win[4][4];
#pragma unroll
      for (int r = 0; r < 4; r++) {
        const float2 a = *(const float2*)&sx[bb][ic][iy + r][ix];
        const float2 c2 = *(const float2*)&sx[bb][ic][iy + r][ix + 2];
        win[r][0] = a.x; win[r][1] = a.y; win[r][2] = c2.x; win[r][3] = c2.y;
      }
#pragma unroll
      for (int oc = 0; oc < 16; oc++) {
        const float* wq = wg + (oc * 8 + ic) * 9;  // uniform -> SGPR
#pragma unroll
        for (int ky = 0; ky < 3; ky++)
#pragma unroll
          for (int kx = 0; kx < 3; kx++) {
            const float wv_ = wq[ky * 3 + kx];
            acc[oc][0] = fmaf(win[ky][kx],         wv_, acc[oc][0]);
            acc[oc][1] = fmaf(win[ky][kx + 1],     wv_, acc[oc][1]);
            acc[oc][2] = fmaf(win[ky + 1][kx],     wv_, acc[oc][2]);
            acc[oc][3] = fmaf(win[ky + 1][kx + 1], wv_, acc[oc][3]);
          }
      }
    }
#pragma unroll
    for (int oc = 0; oc < 16; oc++) {
      const float v = fmaxf(fmaxf(acc[oc][0], acc[oc][1]), fmaxf(acc[oc][2], acc[oc][3])) + bg[oc];
      out[(size_t)((b0 + bb) * 1152 + g * 16 + oc) * 81 + p] = fmaxf(v, 0.f);
    }
  }
}

// ---------------- conv3: (64,1152,9,9) -> k3 (16->32) -> relu -> pool2 -> (64,2304,3,3)
// ocg forced scalar via readfirstlane -> weight addresses uniform -> s_load.
#define C3_NBB 7
__global__ __launch_bounds__(256) void conv3_k(const float* __restrict__ x,
                                               const float* __restrict__ w,
                                               const float* __restrict__ bias,
                                               float* __restrict__ out) {
  const int g = blockIdx.x % NG, b0 = (blockIdx.x / NG) * C3_NBB;
  const int nbb = min(C3_NBB, 64 - b0);
  __shared__ float sx[C3_NBB][16 * 90 + 2];
  for (int bb = 0; bb < nbb; bb++) {
    const float* xp = x + (size_t)((b0 + bb) * 1152 + g * 16) * 81;
    for (int i = threadIdx.x; i < 16 * 81; i += 256) {
      const int ic = i / 81, rem = i % 81, r = rem / 9, c = rem % 9;
      sx[bb][ic * 90 + r * 10 + c] = xp[i];
    }
  }
  __syncthreads();
  const int ocg = __builtin_amdgcn_readfirstlane(threadIdx.x >> 6);  // wave-uniform, scalar
  const float* wg = w + ((size_t)(g * 32 + ocg * 8) * 16) * 9;       // uniform
  const float* bg = bias + g * 32 + ocg * 8;                         // uniform
  const int lane = threadIdx.x & 63;
  const int bb = lane / 9, p = lane % 9;
  if (bb < nbb) {
    const int py = p / 3, px = p % 3, iy = 2 * py, ix = 2 * px;
    const float* sxb = &sx[bb][0];
    float acc[8][4];
#pragma unroll
    for (int o = 0; o < 8; o++)
#pragma unroll
      for (int q = 0; q < 4; q++) acc[o][q] = 0.f;
#pragma unroll
    for (int ic = 0; ic < 16; ic++) {
      float win[4][4];
#pragma unroll
      for (int r = 0; r < 4; r++) {
        const float2 a = *(const float2*)&sxb[ic * 90 + (iy + r) * 10 + ix];
        const float2 c2 = *(const float2*)&sxb[ic * 90 + (iy + r) * 10 + ix + 2];
        win[r][0] = a.x; win[r][1] = a.y; win[r][2] = c2.x; win[r][3] = c2.y;
      }
#pragma unroll
      for (int o8 = 0; o8 < 8; o8++) {
        const float* wq = wg + (o8 * 16 + ic) * 9;   // uniform -> SGPR
#pragma unroll
        for (int ky = 0; ky < 3; ky++)
#pragma unroll
          for (int kx = 0; kx < 3; kx++) {
            const float wv_ = wq[ky * 3 + kx];
            acc[o8][0] = fmaf(win[ky][kx],         wv_, acc[o8][0]);
            acc[o8][1] = fmaf(win[ky][kx + 1],     wv_, acc[o8][1]);
            acc[o8][2] = fmaf(win[ky + 1][kx],     wv_, acc[o8][2]);
            acc[o8][3] = fmaf(win[ky + 1][kx + 1], wv_, acc[o8][3]);
          }
      }
    }
#pragma unroll
    for (int o8 = 0; o8 < 8; o8++) {
      const float v = fmaxf(fmaxf(acc[o8][0], acc[o8][1]), fmaxf(acc[o8][2], acc[o8][3])) + bg[o8];
      out[(size_t)((b0 + bb) * 2304 + g * 32 + ocg * 8 + o8) * 9 + p] = fmaxf(v, 0.f);
    }
  }
}

// ---------------- fused block-diagonal linear1 (288->64) + linear2 (64->2) + bias
__global__ __launch_bounds__(256) void lin_k(const float* __restrict__ h,
                                             const float* __restrict__ w1,
                                             const float* __restrict__ w2,
                                             const float* __restrict__ b2,
                                             float* __restrict__ out) {
  const int g = blockIdx.x % NG, b0 = (blockIdx.x / NG) * 32;
  __shared__ float sw1[64 * 292];
  __shared__ float sf[32 * 300];
  __shared__ float so[32 * 65];
  __shared__ float sw2[2 * 64];
  __shared__ float sb2[2];
  for (int i = threadIdx.x; i < 64 * 288; i += 256) {
    const int o = i / 288, k = i % 288;
    sw1[o * 292 + k] = w1[(size_t)(g * 64 + o) * 20736 + g * 288 + k];
  }
  for (int i = threadIdx.x; i < 32 * 288; i += 256) {
    const int bb = i / 288, k = i % 288;
    sf[bb * 300 + k] = h[(size_t)(b0 + bb) * 20736 + g * 288 + k];
  }
  if (threadIdx.x < 128) {
    const int j = threadIdx.x >> 6, o = threadIdx.x & 63;
    sw2[j * 64 + o] = w2[(size_t)(g * 2 + j) * 4608 + g * 64 + o];
  }
  if (threadIdx.x < 2) sb2[threadIdx.x] = b2[g * 2 + threadIdx.x];
  __syncthreads();
  const int bp = threadIdx.x & 15, oq = threadIdx.x >> 4;
  const int o0 = 4 * oq;
  float acc[2][4];
#pragma unroll
  for (int i = 0; i < 2; i++)
#pragma unroll
    for (int j = 0; j < 4; j++) acc[i][j] = 0.f;
  for (int k4 = 0; k4 < 72; k4++) {
    const float4 f0 = *(const float4*)&sf[bp * 300 + 4 * k4];
    const float4 f1 = *(const float4*)&sf[(bp + 16) * 300 + 4 * k4];
#pragma unroll
    for (int j = 0; j < 4; j++) {
      const float4 wr = *(const float4*)&sw1[(o0 + j) * 292 + 4 * k4];
      acc[0][j] = fmaf(f0.x, wr.x, fmaf(f0.y, wr.y, fmaf(f0.z, wr.z, fmaf(f0.w, wr.w, acc[0][j]))));
      acc[1][j] = fmaf(f1.x, wr.x, fmaf(f1.y, wr.y, fmaf(f1.z, wr.z, fmaf(f1.w, wr.w, acc[1][j]))));
    }
  }
#pragma unroll
  for (int j = 0; j < 4; j++) {
    so[bp * 65 + o0 + j] = acc[0][j];
    so[(bp + 16) * 65 + o0 + j] = acc[1][j];
  }
  __syncthreads();
  if (threadIdx.x < 64) {
    const int bb = threadIdx.x >> 1, j = threadIdx.x & 1;
    float a = sb2[j];
#pragma unroll 8
    for (int o = 0; o < 64; o++) a = fmaf(so[bb * 65 + o], sw2[j * 64 + o], a);
    out[(b0 + bb) * 144 + g * 2 + j] = a;
  }
}

extern "C" void kernel_launch(void* const* d_in, const int* in_sizes, int n_in,
                              void* d_out, int out_size, void* d_ws, size_t ws_size,
                              hipStream_t stream) {
  const float* x   = (const float*)d_in[0];
  const float* w1  = (const float*)d_in[1];
  const float* b1  = (const float*)d_in[2];
  const float* w2  = (const float*)d_in[3];
  const float* b2  = (const float*)d_in[4];
  const float* w3  = (const float*)d_in[5];
  const float* b3  = (const float*)d_in[6];
  const float* l1w = (const float*)d_in[7];
  const float* l2w = (const float*)d_in[8];
  const float* l2b = (const float*)d_in[9];
  float* out = (float*)d_out;

  float* h1 = (float*)d_ws;          // 64*576*21*21
  float* h2 = h1 + 16257024;         // 64*1152*9*9
  float* h3 = h2 + 5971968;          // 64*2304*3*3

  conv1_k<<<dim3(64 * NG * 2), 256, 0, stream>>>(x,  w1, b1, h1);
  conv2_k<<<dim3(22 * NG),     256, 0, stream>>>(h1, w2, b2, h2);
  conv3_k<<<dim3(10 * NG),     256, 0, stream>>>(h2, w3, b3, h3);
  lin_k  <<<dim3(2 * NG),      256, 0, stream>>>(h3, l1w, l2w, l2b, out);
}

// Round 11
// 206.151 us; speedup vs baseline: 1.5607x; 1.5607x over previous
//
#include <hip/hip_runtime.h>

#define NG 72

typedef _Float16 half2f __attribute__((ext_vector_type(2)));

__device__ __forceinline__ unsigned pkrtz(float a, float b) {
  return __builtin_bit_cast(unsigned, __builtin_amdgcn_cvt_pkrtz(a, b));
}
__device__ __forceinline__ float dot2(unsigned win, unsigned wgt, float acc) {
  return __builtin_amdgcn_fdot2(__builtin_bit_cast(half2f, win),
                                __builtin_bit_cast(half2f, wgt), acc, false);
}

// ---------------- prep: pack conv weights as half2 (ic-pairs) into d_ws ----
// wf layout: conv1 [g*8+oc][p<2][t<25] @0 (28800) ; conv2 [g*16+oc][p<4][t<9]
// @28800 (41472) ; conv3 [g*32+oc][p<8][t<9] @70272 (165888). total 236160.
__global__ __launch_bounds__(256) void prep_k(const float* __restrict__ w1,
                                              const float* __restrict__ w2,
                                              const float* __restrict__ w3,
                                              unsigned* __restrict__ wf) {
  const int i = blockIdx.x * 256 + threadIdx.x;
  if (i < 28800) {
    const int t = i % 25, p = (i / 25) & 1, ocg = i / 50;
    const float* base = w1 + (size_t)ocg * 75 + t;
    const float a = base[p * 50];                    // ic = 2p
    const float b = (p == 0) ? base[25] : 0.f;       // ic = 2p+1 (pad ic3=0)
    wf[i] = pkrtz(a, b);
  } else if (i < 70272) {
    const int j = i - 28800;
    const int t = j % 9, p = (j / 9) & 3, ocg = j / 36;
    const float* base = w2 + (size_t)ocg * 72 + t;
    wf[i] = pkrtz(base[2 * p * 9], base[(2 * p + 1) * 9]);
  } else if (i < 236160) {
    const int j = i - 70272;
    const int t = j % 9, p = (j / 9) & 7, ocg = j / 72;
    const float* base = w3 + (size_t)ocg * 144 + t;
    wf[i] = pkrtz(base[2 * p * 9], base[(2 * p + 1) * 9]);
  }
}

// ---------------- conv1: (64,216,46,46) -> k5 g72 (3->8) -> relu -> pool2 ----
// f16 ic-pair dot2: pairs (ic0,ic1),(ic2,0). Weights half2 via SGPR s_load.
__global__ __launch_bounds__(256) void conv1_k(const float* __restrict__ x,
                                               const unsigned* __restrict__ wf,
                                               const float* __restrict__ bias,
                                               float* __restrict__ out) {
  const int blk = blockIdx.x;
  const int b = blk / (NG * 2), rem = blk % (NG * 2), g = rem >> 1, yh = rem & 1;
  const int y0 = yh ? 11 : 0;
  const int ny = yh ? 10 : 11;
  const int r0 = 2 * y0;
  const int nr = yh ? 24 : 26;
  __shared__ unsigned sxp[2][26][48];   // half2(ic2p, ic2p+1) per (r,c)
  const float* xp = x + (size_t)(b * 216 + g * 3) * 2116;
  const int nf4 = (nr * 46) >> 2;       // 299 or 276, exact
  const float4* q0 = (const float4*)(xp + r0 * 46);
  const float4* q1 = (const float4*)(xp + 2116 + r0 * 46);
  const float4* q2 = (const float4*)(xp + 2 * 2116 + r0 * 46);
  for (int i = threadIdx.x; i < nf4; i += 256) {
    const float4 a = q0[i], c1 = q1[i], c2 = q2[i];
#pragma unroll
    for (int j = 0; j < 4; j++) {
      const int k = 4 * i + j, r = k / 46, cc = k % 46;
      sxp[0][r][cc] = pkrtz((&a.x)[j], (&c1.x)[j]);
      sxp[1][r][cc] = pkrtz((&c2.x)[j], 0.f);
    }
  }
  __syncthreads();
  const unsigned* wgq = wf + (size_t)(g * 8) * 50;   // [oc][p][25], uniform
  const float* bg = bias + g * 8;                    // uniform
  const int tid = threadIdx.x;
  if (tid < ny * 21) {
    const int yl = tid / 21, px = tid % 21;
    const int iy = 2 * yl, ix = 2 * px;
    float acc[8][4];
#pragma unroll
    for (int o = 0; o < 8; o++)
#pragma unroll
      for (int q = 0; q < 4; q++) acc[o][q] = 0.f;
#pragma unroll 1   // sequential ic-pair phases: keep winp live range small
    for (int p = 0; p < 2; p++) {
      unsigned winp[6][6];
#pragma unroll
      for (int r = 0; r < 6; r++)
#pragma unroll
        for (int c = 0; c < 6; c++) winp[r][c] = sxp[p][iy + r][ix + c];
#pragma unroll
      for (int oc = 0; oc < 8; oc++) {
        const unsigned* wq = wgq + (oc * 2 + p) * 25;   // uniform -> SGPR
#pragma unroll
        for (int ky = 0; ky < 5; ky++)
#pragma unroll
          for (int kx = 0; kx < 5; kx++) {
            const unsigned wv = wq[ky * 5 + kx];
            acc[oc][0] = dot2(winp[ky][kx],         wv, acc[oc][0]);
            acc[oc][1] = dot2(winp[ky][kx + 1],     wv, acc[oc][1]);
            acc[oc][2] = dot2(winp[ky + 1][kx],     wv, acc[oc][2]);
            acc[oc][3] = dot2(winp[ky + 1][kx + 1], wv, acc[oc][3]);
          }
      }
    }
#pragma unroll
    for (int oc = 0; oc < 8; oc++) {
      const float v = fmaxf(fmaxf(acc[oc][0], acc[oc][1]), fmaxf(acc[oc][2], acc[oc][3])) + bg[oc];
      out[(size_t)(b * 576 + g * 8 + oc) * 441 + (y0 + yl) * 21 + px] = fmaxf(v, 0.f);
    }
  }
}

// ---------------- conv2: (64,576,21,21) -> k3 (8->16) -> relu -> pool2 ------
#define C2_NBB 3
__global__ __launch_bounds__(256) void conv2_k(const float* __restrict__ x,
                                               const unsigned* __restrict__ wf,
                                               const float* __restrict__ bias,
                                               float* __restrict__ out) {
  const int g = blockIdx.x % NG, b0 = (blockIdx.x / NG) * C2_NBB;
  const int nbb = min(C2_NBB, 64 - b0);
  __shared__ unsigned sxp[C2_NBB][4][21][22];   // half2 ic-pairs
  for (int bb = 0; bb < nbb; bb++) {
    const float* xp = x + (size_t)((b0 + bb) * 576 + g * 8) * 441;
    for (int i = threadIdx.x; i < 4 * 441; i += 256) {
      const int p = i / 441, e = i % 441, r = e / 21, c = e % 21;
      sxp[bb][p][r][c] = pkrtz(xp[2 * p * 441 + e], xp[(2 * p + 1) * 441 + e]);
    }
  }
  __syncthreads();
  const unsigned* wg = wf + (size_t)(g * 16) * 36;   // [oc][p][9], uniform
  const float* bg = bias + g * 16;                   // uniform
  for (int u = threadIdx.x; u < nbb * 81; u += 256) {
    const int bb = u / 81, pp = u % 81, py = pp / 9, px = pp % 9;
    const int iy = 2 * py, ix = 2 * px;
    float acc[16][4];
#pragma unroll
    for (int o = 0; o < 16; o++)
#pragma unroll
      for (int q = 0; q < 4; q++) acc[o][q] = 0.f;
#pragma unroll 1   // sequential ic-pair phases
    for (int p = 0; p < 4; p++) {
      unsigned winp[4][4];
#pragma unroll
      for (int r = 0; r < 4; r++)
#pragma unroll
        for (int c = 0; c < 4; c++) winp[r][c] = sxp[bb][p][iy + r][ix + c];
#pragma unroll
      for (int oc = 0; oc < 16; oc++) {
        const unsigned* wq = wg + (oc * 4 + p) * 9;   // uniform -> SGPR
#pragma unroll
        for (int ky = 0; ky < 3; ky++)
#pragma unroll
          for (int kx = 0; kx < 3; kx++) {
            const unsigned wv = wq[ky * 3 + kx];
            acc[oc][0] = dot2(winp[ky][kx],         wv, acc[oc][0]);
            acc[oc][1] = dot2(winp[ky][kx + 1],     wv, acc[oc][1]);
            acc[oc][2] = dot2(winp[ky + 1][kx],     wv, acc[oc][2]);
            acc[oc][3] = dot2(winp[ky + 1][kx + 1], wv, acc[oc][3]);
          }
      }
    }
#pragma unroll
    for (int oc = 0; oc < 16; oc++) {
      const float v = fmaxf(fmaxf(acc[oc][0], acc[oc][1]), fmaxf(acc[oc][2], acc[oc][3])) + bg[oc];
      out[(size_t)((b0 + bb) * 1152 + g * 16 + oc) * 81 + pp] = fmaxf(v, 0.f);
    }
  }
}

// ---------------- conv3: (64,1152,9,9) -> k3 (16->32) -> relu -> pool2 ------
#define C3_NBB 7
__global__ __launch_bounds__(256) void conv3_k(const float* __restrict__ x,
                                               const unsigned* __restrict__ wf,
                                               const float* __restrict__ bias,
                                               float* __restrict__ out) {
  const int g = blockIdx.x % NG, b0 = (blockIdx.x / NG) * C3_NBB;
  const int nbb = min(C3_NBB, 64 - b0);
  __shared__ unsigned sxp[C3_NBB][8][9][10];   // half2 ic-pairs, pitch 10
  for (int bb = 0; bb < nbb; bb++) {
    const float* xp = x + (size_t)((b0 + bb) * 1152 + g * 16) * 81;
    for (int i = threadIdx.x; i < 8 * 81; i += 256) {
      const int p = i / 81, e = i % 81, r = e / 9, c = e % 9;
      sxp[bb][p][r][c] = pkrtz(xp[2 * p * 81 + e], xp[(2 * p + 1) * 81 + e]);
    }
  }
  __syncthreads();
  const int ocg = __builtin_amdgcn_readfirstlane(threadIdx.x >> 6);  // uniform
  const unsigned* wg = wf + ((size_t)(g * 32 + ocg * 8)) * 72;       // [oc][p][9]
  const float* bg = bias + g * 32 + ocg * 8;                         // uniform
  const int lane = threadIdx.x & 63;
  const int bb = lane / 9, pp = lane % 9;
  if (bb < nbb) {
    const int py = pp / 3, px = pp % 3, iy = 2 * py, ix = 2 * px;
    float acc[8][4];
#pragma unroll
    for (int o = 0; o < 8; o++)
#pragma unroll
      for (int q = 0; q < 4; q++) acc[o][q] = 0.f;
#pragma unroll 1
    for (int p = 0; p < 8; p++) {
      unsigned winp[4][4];
#pragma unroll
      for (int r = 0; r < 4; r++)
#pragma unroll
        for (int c = 0; c < 4; c++) winp[r][c] = sxp[bb][p][iy + r][ix + c];
#pragma unroll
      for (int o8 = 0; o8 < 8; o8++) {
        const unsigned* wq = wg + (o8 * 8 + p) * 9;   // uniform -> SGPR
#pragma unroll
        for (int ky = 0; ky < 3; ky++)
#pragma unroll
          for (int kx = 0; kx < 3; kx++) {
            const unsigned wv = wq[ky * 3 + kx];
            acc[o8][0] = dot2(winp[ky][kx],         wv, acc[o8][0]);
            acc[o8][1] = dot2(winp[ky][kx + 1],     wv, acc[o8][1]);
            acc[o8][2] = dot2(winp[ky + 1][kx],     wv, acc[o8][2]);
            acc[o8][3] = dot2(winp[ky + 1][kx + 1], wv, acc[o8][3]);
          }
      }
    }
#pragma unroll
    for (int o8 = 0; o8 < 8; o8++) {
      const float v = fmaxf(fmaxf(acc[o8][0], acc[o8][1]), fmaxf(acc[o8][2], acc[o8][3])) + bg[o8];
      out[(size_t)((b0 + bb) * 2304 + g * 32 + ocg * 8 + o8) * 9 + pp] = fmaxf(v, 0.f);
    }
  }
}

// ---------------- fused block-diagonal linear1 (288->64) + linear2 (64->2) + bias
__global__ __launch_bounds__(256) void lin_k(const float* __restrict__ h,
                                             const float* __restrict__ w1,
                                             const float* __restrict__ w2,
                                             const float* __restrict__ b2,
                                             float* __restrict__ out) {
  const int g = blockIdx.x % NG, b0 = (blockIdx.x / NG) * 32;
  __shared__ float sw1[64 * 292];
  __shared__ float sf[32 * 300];
  __shared__ float so[32 * 65];
  __shared__ float sw2[2 * 64];
  __shared__ float sb2[2];
  for (int i = threadIdx.x; i < 64 * 288; i += 256) {
    const int o = i / 288, k = i % 288;
    sw1[o * 292 + k] = w1[(size_t)(g * 64 + o) * 20736 + g * 288 + k];
  }
  for (int i = threadIdx.x; i < 32 * 288; i += 256) {
    const int bb = i / 288, k = i % 288;
    sf[bb * 300 + k] = h[(size_t)(b0 + bb) * 20736 + g * 288 + k];
  }
  if (threadIdx.x < 128) {
    const int j = threadIdx.x >> 6, o = threadIdx.x & 63;
    sw2[j * 64 + o] = w2[(size_t)(g * 2 + j) * 4608 + g * 64 + o];
  }
  if (threadIdx.x < 2) sb2[threadIdx.x] = b2[g * 2 + threadIdx.x];
  __syncthreads();
  const int bp = threadIdx.x & 15, oq = threadIdx.x >> 4;
  const int o0 = 4 * oq;
  float acc[2][4];
#pragma unroll
  for (int i = 0; i < 2; i++)
#pragma unroll
    for (int j = 0; j < 4; j++) acc[i][j] = 0.f;
  for (int k4 = 0; k4 < 72; k4++) {
    const float4 f0 = *(const float4*)&sf[bp * 300 + 4 * k4];
    const float4 f1 = *(const float4*)&sf[(bp + 16) * 300 + 4 * k4];
#pragma unroll
    for (int j = 0; j < 4; j++) {
      const float4 wr = *(const float4*)&sw1[(o0 + j) * 292 + 4 * k4];
      acc[0][j] = fmaf(f0.x, wr.x, fmaf(f0.y, wr.y, fmaf(f0.z, wr.z, fmaf(f0.w, wr.w, acc[0][j]))));
      acc[1][j] = fmaf(f1.x, wr.x, fmaf(f1.y, wr.y, fmaf(f1.z, wr.z, fmaf(f1.w, wr.w, acc[1][j]))));
    }
  }
#pragma unroll
  for (int j = 0; j < 4; j++) {
    so[bp * 65 + o0 + j] = acc[0][j];
    so[(bp + 16) * 65 + o0 + j] = acc[1][j];
  }
  __syncthreads();
  if (threadIdx.x < 64) {
    const int bb = threadIdx.x >> 1, j = threadIdx.x & 1;
    float a = sb2[j];
#pragma unroll 8
    for (int o = 0; o < 64; o++) a = fmaf(so[bb * 65 + o], sw2[j * 64 + o], a);
    out[(b0 + bb) * 144 + g * 2 + j] = a;
  }
}

extern "C" void kernel_launch(void* const* d_in, const int* in_sizes, int n_in,
                              void* d_out, int out_size, void* d_ws, size_t ws_size,
                              hipStream_t stream) {
  const float* x   = (const float*)d_in[0];
  const float* w1  = (const float*)d_in[1];
  const float* b1  = (const float*)d_in[2];
  const float* w2  = (const float*)d_in[3];
  const float* b2  = (const float*)d_in[4];
  const float* w3  = (const float*)d_in[5];
  const float* b3  = (const float*)d_in[6];
  const float* l1w = (const float*)d_in[7];
  const float* l2w = (const float*)d_in[8];
  const float* l2b = (const float*)d_in[9];
  float* out = (float*)d_out;

  float* h1 = (float*)d_ws;          // 64*576*21*21
  float* h2 = h1 + 16257024;         // 64*1152*9*9
  float* h3 = h2 + 5971968;          // 64*2304*3*3
  unsigned* wf = (unsigned*)(h3 + 1327104);  // packed f16 weights (236160 u32)

  prep_k <<<dim3(923),         256, 0, stream>>>(w1, w2, w3, wf);
  conv1_k<<<dim3(64 * NG * 2), 256, 0, stream>>>(x,  wf,         b1, h1);
  conv2_k<<<dim3(22 * NG),     256, 0, stream>>>(h1, wf + 28800, b2, h2);
  conv3_k<<<dim3(10 * NG),     256, 0, stream>>>(h2, wf + 70272, b3, h3);
  lin_k  <<<dim3(2 * NG),      256, 0, stream>>>(h3, l1w, l2w, l2b, out);
}